// Round 5
// baseline (746.424 us; speedup 1.0000x reference)
//
#include <hip/hip_runtime.h>
#include <hip/hip_bf16.h>
#include <cstdint>

#define SDIM 200
#define HDIM 128
#define IDIM 4
#define BDIM 1024
#define LDK 72      // bf16 staging leading dim per 64-wide K-half (144 B rows)
#define LDEF 132    // fp32 epilogue / routing-tile leading dim (528 B rows)

typedef __attribute__((ext_vector_type(8))) short short8;
typedef __attribute__((ext_vector_type(4))) float f32x4;

__device__ __forceinline__ ushort f32_to_bf16u(float f) {
    uint32_t u = __builtin_bit_cast(uint32_t, f);
    u += 0x7FFFu + ((u >> 16) & 1u);   // RNE
    return (ushort)(u >> 16);
}
__device__ __forceinline__ float bf16u_to_f32(ushort h) {
    uint32_t u = ((uint32_t)h) << 16;
    return __builtin_bit_cast(float, u);
}
__device__ __forceinline__ void split8(const float* p, uint4* hi, uint4* lo) {
    union { ushort u[8]; uint4 v; } xh, xl;
    #pragma unroll
    for (int j = 0; j < 8; ++j) {
        float f = p[j];
        ushort h = f32_to_bf16u(f);
        float r = f - bf16u_to_f32(h);
        xh.u[j] = h;
        xl.u[j] = f32_to_bf16u(r);
    }
    *hi = xh.v; *lo = xl.v;
}

// ---------------------------------------------------------------------------
// Kernel 0: one-time split of fp32 src into bf16 hi/lo planes.
// ---------------------------------------------------------------------------
__global__ __launch_bounds__(256) void presplit(const float* __restrict__ src,
                                                ushort* __restrict__ hi,
                                                ushort* __restrict__ lo, int n8) {
    int idx = blockIdx.x * blockDim.x + threadIdx.x;
    int stride = gridDim.x * blockDim.x;
    for (int g = idx; g < n8; g += stride) {
        const float* p = src + (size_t)g * 8;
        uint4 h4, l4;
        split8(p, &h4, &l4);
        *(uint4*)(hi + (size_t)g * 8) = h4;
        *(uint4*)(lo + (size_t)g * 8) = l4;
    }
}

// ---------------------------------------------------------------------------
// Kernel 1 (fast): hat from pre-split bf16 planes. 3-stream MFMA, fp32 out.
// One block per (s, i, 128-b-tile). K=128 in two 64-halves. LDS 73,728 B.
// ---------------------------------------------------------------------------
__global__ __launch_bounds__(256) void hat_gemm_fast(const ushort* __restrict__ itemH,
                                                     const ushort* __restrict__ itemL,
                                                     const ushort* __restrict__ wH,
                                                     const ushort* __restrict__ wL,
                                                     float* __restrict__ hat,
                                                     int b0, int nbt) {
    __shared__ ushort lds[4 * 128 * LDK];
    ushort* Ah = lds;
    ushort* Al = lds + 128 * LDK;
    ushort* Wh = lds + 2 * 128 * LDK;
    ushort* Wl = lds + 3 * 128 * LDK;
    float*  ef = (float*)lds;            // epilogue overlay [128][LDEF] = 67,584 B

    const int blk = blockIdx.x;
    const int s  = blk / (IDIM * nbt);
    const int r  = blk % (IDIM * nbt);
    const int ii = r / nbt;
    const int bt = r % nbt;
    const int t  = threadIdx.x;

    const int wave = t >> 6, lane = t & 63;
    const int wm = wave >> 1, wn = wave & 1;
    const int m0 = lane & 15, q = lane >> 4;

    f32x4 acc[4][4];
    #pragma unroll
    for (int tm = 0; tm < 4; ++tm)
        #pragma unroll
        for (int tn = 0; tn < 4; ++tn)
            acc[tm][tn] = (f32x4){0.f, 0.f, 0.f, 0.f};

    #pragma unroll
    for (int st = 0; st < 2; ++st) {
        const int kbase = st * 64;
        if (st) __syncthreads();
        #pragma unroll
        for (int c = t; c < 1024; c += 256) {
            int row = c >> 3, g = c & 7;
            size_t aoff = ((size_t)(b0 + bt * 128 + row) * SDIM + s) * HDIM + kbase + g * 8;
            *(uint4*)(&Ah[row * LDK + g * 8]) = *(const uint4*)(itemH + aoff);
            *(uint4*)(&Al[row * LDK + g * 8]) = *(const uint4*)(itemL + aoff);
            size_t woff = ((size_t)s * (IDIM * HDIM) + ii * HDIM + row) * HDIM + kbase + g * 8;
            *(uint4*)(&Wh[row * LDK + g * 8]) = *(const uint4*)(wH + woff);
            *(uint4*)(&Wl[row * LDK + g * 8]) = *(const uint4*)(wL + woff);
        }
        __syncthreads();

        #pragma unroll
        for (int kk = 0; kk < 2; ++kk) {
            const int kof = kk * 32 + q * 8;
            short8 ah[4], al[4], bh[4], bl[4];
            #pragma unroll
            for (int tm = 0; tm < 4; ++tm) {
                int ro = (wm * 64 + tm * 16 + m0) * LDK + kof;
                ah[tm] = *(const short8*)(&Ah[ro]);
                al[tm] = *(const short8*)(&Al[ro]);
            }
            #pragma unroll
            for (int tn = 0; tn < 4; ++tn) {
                int ro = (wn * 64 + tn * 16 + m0) * LDK + kof;
                bh[tn] = *(const short8*)(&Wh[ro]);
                bl[tn] = *(const short8*)(&Wl[ro]);
            }
            #pragma unroll
            for (int tm = 0; tm < 4; ++tm)
                #pragma unroll
                for (int tn = 0; tn < 4; ++tn) {
                    acc[tm][tn] = __builtin_amdgcn_mfma_f32_16x16x32_bf16(
                        ah[tm], bl[tn], acc[tm][tn], 0, 0, 0);
                    acc[tm][tn] = __builtin_amdgcn_mfma_f32_16x16x32_bf16(
                        al[tm], bh[tn], acc[tm][tn], 0, 0, 0);
                    acc[tm][tn] = __builtin_amdgcn_mfma_f32_16x16x32_bf16(
                        ah[tm], bh[tn], acc[tm][tn], 0, 0, 0);
                }
        }
    }
    __syncthreads();

    #pragma unroll
    for (int tm = 0; tm < 4; ++tm) {
        #pragma unroll
        for (int tn = 0; tn < 4; ++tn) {
            int col = wn * 64 + tn * 16 + m0;
            #pragma unroll
            for (int rg = 0; rg < 4; ++rg) {
                int row = wm * 64 + tm * 16 + q * 4 + rg;
                ef[row * LDEF + col] = acc[tm][tn][rg];
            }
        }
    }
    __syncthreads();
    #pragma unroll
    for (int c = t; c < 4096; c += 256) {
        int row = c >> 5, cc = c & 31;
        int bl_ = bt * 128 + row;
        float4 v = *(const float4*)(&ef[row * LDEF + cc * 4]);
        *(float4*)(hat + (((size_t)bl_ * IDIM + ii) * SDIM + s) * HDIM + cc * 4) = v;
    }
}

// ---------------------------------------------------------------------------
// Kernel 1 (fallback, R4-proven): inline split, fp32 inputs.
// ---------------------------------------------------------------------------
__global__ __launch_bounds__(256) void hat_gemm(const float* __restrict__ item,
                                                const float* __restrict__ w,
                                                float* __restrict__ hat,
                                                int b0, int nbt) {
    __shared__ ushort lds[4 * 128 * LDK];
    ushort* Ah = lds;
    ushort* Al = lds + 128 * LDK;
    ushort* Wh = lds + 2 * 128 * LDK;
    ushort* Wl = lds + 3 * 128 * LDK;
    float*  ef = (float*)lds;

    const int blk = blockIdx.x;
    const int s  = blk / (IDIM * nbt);
    const int r  = blk % (IDIM * nbt);
    const int ii = r / nbt;
    const int bt = r % nbt;
    const int t  = threadIdx.x;

    const float* itemBase = item + ((size_t)(b0 + bt * 128) * SDIM + s) * HDIM;
    const float* wBase    = w + ((size_t)s * (IDIM * HDIM) + (size_t)ii * HDIM) * HDIM;

    const int wave = t >> 6, lane = t & 63;
    const int wm = wave >> 1, wn = wave & 1;
    const int m0 = lane & 15, q = lane >> 4;

    f32x4 acc[4][4];
    #pragma unroll
    for (int tm = 0; tm < 4; ++tm)
        #pragma unroll
        for (int tn = 0; tn < 4; ++tn)
            acc[tm][tn] = (f32x4){0.f, 0.f, 0.f, 0.f};

    #pragma unroll
    for (int st = 0; st < 2; ++st) {
        const int kbase = st * 64;
        if (st) __syncthreads();
        #pragma unroll
        for (int c = t; c < 1024; c += 256) {
            int row = c >> 3, g = c & 7;
            uint4 hi, lo;
            split8(itemBase + (size_t)row * (SDIM * HDIM) + kbase + g * 8, &hi, &lo);
            *(uint4*)(&Ah[row * LDK + g * 8]) = hi;
            *(uint4*)(&Al[row * LDK + g * 8]) = lo;
            split8(wBase + (size_t)row * HDIM + kbase + g * 8, &hi, &lo);
            *(uint4*)(&Wh[row * LDK + g * 8]) = hi;
            *(uint4*)(&Wl[row * LDK + g * 8]) = lo;
        }
        __syncthreads();

        #pragma unroll
        for (int kk = 0; kk < 2; ++kk) {
            const int kof = kk * 32 + q * 8;
            short8 ah[4], al[4], bh[4], bl[4];
            #pragma unroll
            for (int tm = 0; tm < 4; ++tm) {
                int ro = (wm * 64 + tm * 16 + m0) * LDK + kof;
                ah[tm] = *(const short8*)(&Ah[ro]);
                al[tm] = *(const short8*)(&Al[ro]);
            }
            #pragma unroll
            for (int tn = 0; tn < 4; ++tn) {
                int ro = (wn * 64 + tn * 16 + m0) * LDK + kof;
                bh[tn] = *(const short8*)(&Wh[ro]);
                bl[tn] = *(const short8*)(&Wl[ro]);
            }
            #pragma unroll
            for (int tm = 0; tm < 4; ++tm)
                #pragma unroll
                for (int tn = 0; tn < 4; ++tn) {
                    acc[tm][tn] = __builtin_amdgcn_mfma_f32_16x16x32_bf16(
                        ah[tm], bl[tn], acc[tm][tn], 0, 0, 0);
                    acc[tm][tn] = __builtin_amdgcn_mfma_f32_16x16x32_bf16(
                        al[tm], bh[tn], acc[tm][tn], 0, 0, 0);
                    acc[tm][tn] = __builtin_amdgcn_mfma_f32_16x16x32_bf16(
                        ah[tm], bh[tn], acc[tm][tn], 0, 0, 0);
                }
        }
    }
    __syncthreads();

    #pragma unroll
    for (int tm = 0; tm < 4; ++tm) {
        #pragma unroll
        for (int tn = 0; tn < 4; ++tn) {
            int col = wn * 64 + tn * 16 + m0;
            #pragma unroll
            for (int rg = 0; rg < 4; ++rg) {
                int row = wm * 64 + tm * 16 + q * 4 + rg;
                ef[row * LDEF + col] = acc[tm][tn][rg];
            }
        }
    }
    __syncthreads();
    #pragma unroll
    for (int c = t; c < 4096; c += 256) {
        int row = c >> 5, cc = c & 31;
        int bl_ = bt * 128 + row;
        float4 v = *(const float4*)(&ef[row * LDEF + cc * 4]);
        *(float4*)(hat + (((size_t)bl_ * IDIM + ii) * SDIM + s) * HDIM + cc * 4) = v;
    }
}

// ---------------------------------------------------------------------------
// Kernel 2: routing, one block per b, 4 i-tiles sequentially with register
// prefetch of the next tile. 1024 threads; LDS ~113 KB; all fp32.
// ---------------------------------------------------------------------------
__global__ __launch_bounds__(1024) void routing2(const float* __restrict__ hat,
                                                 const int* __restrict__ mask,
                                                 float* __restrict__ out, int b0) {
    __shared__ float hs[SDIM * LDEF];      // 105,600 B
    __shared__ float cw[SDIM];
    __shared__ float ew[SDIM];
    __shared__ float swl[SDIM];
    __shared__ float icp[8 * HDIM];
    __shared__ float ics[HDIM];
    __shared__ int   mk[SDIM];

    const int bl = blockIdx.x, b = b0 + bl;
    const int t = threadIdx.x;
    const int lane = t & 63, wv = t >> 6;
    const float* base = hat + (size_t)bl * IDIM * SDIM * HDIM;

    if (t < SDIM) mk[t] = mask[(size_t)b * SDIM + t];
    for (int c = t; c < 6400; c += 1024) {
        int row = c >> 5, cc = c & 31;
        *(float4*)(&hs[row * LDEF + cc * 4]) = *(const float4*)(base + (size_t)row * HDIM + cc * 4);
    }

    for (int ii = 0; ii < IDIM; ++ii) {
        float4 pf[7];
        if (ii + 1 < IDIM) {
            const float* nb = base + (size_t)(ii + 1) * SDIM * HDIM;
            #pragma unroll
            for (int j = 0; j < 7; ++j) {
                int c = t + j * 1024;
                if (c < 6400) pf[j] = *(const float4*)(nb + (size_t)(c >> 5) * HDIM + (c & 31) * 4);
            }
        }
        if (t < SDIM) cw[t] = 0.0f;
        __syncthreads();   // hs + cw ready

        for (int iter = 0; iter < 3; ++iter) {
            // softmax (waves 0-3, redundant shuffle reductions; others idle to barrier)
            float e = 0.0f;
            if (wv < 4) {
                float m = -1e30f;
                for (int sj = lane; sj < SDIM; sj += 64) m = fmaxf(m, cw[sj]);
                #pragma unroll
                for (int off = 32; off > 0; off >>= 1) m = fmaxf(m, __shfl_xor(m, off));
                if (t < SDIM) { e = expf(cw[t] - m); ew[t] = e; }
            }
            __syncthreads();
            if (wv < 4) {
                float d = 0.0f;
                for (int sj = lane; sj < SDIM; sj += 64) d += ew[sj];
                #pragma unroll
                for (int off = 32; off > 0; off >>= 1) d += __shfl_xor(d, off);
                if (t < SDIM) swl[t] = mk[t] ? e / d : 0.0f;
            }
            __syncthreads();
            // ic partials: 8 s-stripes x 128 h (all 16 waves)
            {
                int h = t & 127, stripe = t >> 7;
                float a = 0.0f;
                for (int sj = stripe; sj < SDIM; sj += 8)
                    a = fmaf(swl[sj], hs[sj * LDEF + h], a);
                icp[stripe * HDIM + h] = a;
            }
            __syncthreads();   // icp ready; hs reads of this pass done

            if (iter < 2) {
                if (wv == 0) {
                    float i0 = 0.f, i1 = 0.f;
                    #pragma unroll
                    for (int st = 0; st < 8; ++st) {
                        i0 += icp[st * HDIM + lane];
                        i1 += icp[st * HDIM + lane + 64];
                    }
                    float p = i0 * i0 + i1 * i1;
                    #pragma unroll
                    for (int off = 32; off > 0; off >>= 1) p += __shfl_xor(p, off);
                    float fac = p / (1.0f + p) / sqrtf(p + 1e-9f);
                    ics[lane] = i0 * fac;
                    ics[lane + 64] = i1 * fac;
                }
                __syncthreads();
                // delta: 800 threads = 200 s x 4 h-chunks (interleaved h: bank-clean)
                if (t < 800) {
                    int s = t >> 2, c4 = t & 3;
                    float d = 0.0f;
                    #pragma unroll
                    for (int k = 0; k < 8; ++k) {
                        int h = c4 * 4 + k * 16;
                        float4 hv = *(const float4*)(&hs[s * LDEF + h]);
                        float4 iv = *(const float4*)(&ics[h]);
                        d = fmaf(hv.x, iv.x, fmaf(hv.y, iv.y, fmaf(hv.z, iv.z, fmaf(hv.w, iv.w, d))));
                    }
                    d += __shfl_xor(d, 1);
                    d += __shfl_xor(d, 2);
                    if (c4 == 0) cw[s] += d;
                }
                __syncthreads();
            }
        }
        // post final-ic barrier: hs is free -> install prefetched tile; wave 0 emits output
        if (ii + 1 < IDIM) {
            #pragma unroll
            for (int j = 0; j < 7; ++j) {
                int c = t + j * 1024;
                if (c < 6400) *(float4*)(&hs[(c >> 5) * LDEF + (c & 31) * 4]) = pf[j];
            }
        }
        if (wv == 0) {
            float i0 = 0.f, i1 = 0.f;
            #pragma unroll
            for (int st = 0; st < 8; ++st) {
                i0 += icp[st * HDIM + lane];
                i1 += icp[st * HDIM + lane + 64];
            }
            float p = i0 * i0 + i1 * i1;
            #pragma unroll
            for (int off = 32; off > 0; off >>= 1) p += __shfl_xor(p, off);
            float fac = p / (1.0f + p) / sqrtf(p + 1e-9f);
            out[((size_t)b * IDIM + ii) * HDIM + lane] = i0 * fac;
            out[((size_t)b * IDIM + ii) * HDIM + lane + 64] = i1 * fac;
        }
        __syncthreads();
    }
}

extern "C" void kernel_launch(void* const* d_in, const int* in_sizes, int n_in,
                              void* d_out, int out_size, void* d_ws, size_t ws_size,
                              hipStream_t stream) {
    const float* item = nullptr;
    const int*   msk  = nullptr;
    const float* w    = nullptr;
    for (int i = 0; i < n_in; ++i) {
        if (in_sizes[i] == BDIM * SDIM * HDIM)             item = (const float*)d_in[i];
        else if (in_sizes[i] == BDIM * SDIM)               msk  = (const int*)d_in[i];
        else if (in_sizes[i] == SDIM * IDIM * HDIM * HDIM) w    = (const float*)d_in[i];
    }
    if (!item) item = (const float*)d_in[0];
    if (!msk)  msk  = (const int*)d_in[1];
    if (!w)    w    = (const float*)d_in[2];

    float* out = (float*)d_out;
    const size_t perB = (size_t)IDIM * SDIM * HDIM * sizeof(float);   // 409,600
    const size_t nItem = (size_t)BDIM * SDIM * HDIM;                  // 26,214,400
    const size_t nW    = (size_t)SDIM * IDIM * HDIM * HDIM;           // 13,107,200
    const size_t planes = 2 * nItem * 2 + 2 * nW * 2;                 // 157,286,400 B

    if (ws_size >= planes + 128 * perB) {
        // fast path: pre-split planes + bf16-plane GEMM
        ushort* iH = (ushort*)d_ws;
        ushort* iL = iH + nItem;
        ushort* wH = iL + nItem;
        ushort* wL = wH + nW;
        float*  hat = (float*)((char*)d_ws + planes);

        presplit<<<4096, 256, 0, stream>>>(item, iH, iL, (int)(nItem / 8));
        presplit<<<2048, 256, 0, stream>>>(w, wH, wL, (int)(nW / 8));

        size_t hatCap = (ws_size - planes) / perB;
        int chunk = (hatCap >= BDIM) ? BDIM : (int)((hatCap / 128) * 128);
        if (chunk < 128) chunk = 128;
        for (int bb = 0; bb < BDIM; bb += chunk) {
            int cb = (BDIM - bb < chunk) ? (BDIM - bb) : chunk;
            int nbt = cb / 128;
            hat_gemm_fast<<<SDIM * IDIM * nbt, 256, 0, stream>>>(iH, iL, wH, wL, hat, bb, nbt);
            routing2<<<cb, 1024, 0, stream>>>(hat, msk, out, bb);
        }
    } else {
        // fallback: R4-proven inline-split GEMM
        float* hat = (float*)d_ws;
        size_t hatCap = ws_size / perB;
        int chunk = (hatCap >= BDIM) ? BDIM : (int)((hatCap / 128) * 128);
        if (chunk < 128) chunk = 128;
        for (int bb = 0; bb < BDIM; bb += chunk) {
            int cb = (BDIM - bb < chunk) ? (BDIM - bb) : chunk;
            int nbt = cb / 128;
            hat_gemm<<<SDIM * IDIM * nbt, 256, 0, stream>>>(item, w, hat, bb, nbt);
            routing2<<<cb, 1024, 0, stream>>>(hat, msk, out, bb);
        }
    }
}

// Round 6
// 667.283 us; speedup vs baseline: 1.1186x; 1.1186x over previous
//
#include <hip/hip_runtime.h>
#include <hip/hip_bf16.h>
#include <cstdint>

#define SDIM 200
#define HDIM 128
#define IDIM 4
#define BDIM 1024
#define LDK 72      // bf16 staging leading dim per 64-wide K-half (144 B rows)
#define LDEF 132    // fp32 epilogue / routing-tile leading dim (528 B rows)

typedef __attribute__((ext_vector_type(8))) short short8;
typedef __attribute__((ext_vector_type(4))) float f32x4;

__device__ __forceinline__ ushort f32_to_bf16u(float f) {
    uint32_t u = __builtin_bit_cast(uint32_t, f);
    u += 0x7FFFu + ((u >> 16) & 1u);   // RNE
    return (ushort)(u >> 16);
}
__device__ __forceinline__ float bf16u_to_f32(ushort h) {
    uint32_t u = ((uint32_t)h) << 16;
    return __builtin_bit_cast(float, u);
}
__device__ __forceinline__ void split8(const float* p, uint4* hi, uint4* lo) {
    union { ushort u[8]; uint4 v; } xh, xl;
    #pragma unroll
    for (int j = 0; j < 8; ++j) {
        float f = p[j];
        ushort h = f32_to_bf16u(f);
        float r = f - bf16u_to_f32(h);
        xh.u[j] = h;
        xl.u[j] = f32_to_bf16u(r);
    }
    *hi = xh.v; *lo = xl.v;
}

// ---------------------------------------------------------------------------
// Kernel 1 (R4-proven): hat[bl,i,s,h'] = sum_h item*w, split-bf16 3-stream MFMA.
// ---------------------------------------------------------------------------
__global__ __launch_bounds__(256) void hat_gemm(const float* __restrict__ item,
                                                const float* __restrict__ w,
                                                float* __restrict__ hat,
                                                int b0, int nbt) {
    __shared__ ushort lds[4 * 128 * LDK];
    ushort* Ah = lds;
    ushort* Al = lds + 128 * LDK;
    ushort* Wh = lds + 2 * 128 * LDK;
    ushort* Wl = lds + 3 * 128 * LDK;
    float*  ef = (float*)lds;

    const int blk = blockIdx.x;
    const int s  = blk / (IDIM * nbt);
    const int r  = blk % (IDIM * nbt);
    const int ii = r / nbt;
    const int bt = r % nbt;
    const int t  = threadIdx.x;

    const float* itemBase = item + ((size_t)(b0 + bt * 128) * SDIM + s) * HDIM;
    const float* wBase    = w + ((size_t)s * (IDIM * HDIM) + (size_t)ii * HDIM) * HDIM;

    const int wave = t >> 6, lane = t & 63;
    const int wm = wave >> 1, wn = wave & 1;
    const int m0 = lane & 15, q = lane >> 4;

    f32x4 acc[4][4];
    #pragma unroll
    for (int tm = 0; tm < 4; ++tm)
        #pragma unroll
        for (int tn = 0; tn < 4; ++tn)
            acc[tm][tn] = (f32x4){0.f, 0.f, 0.f, 0.f};

    #pragma unroll
    for (int st = 0; st < 2; ++st) {
        const int kbase = st * 64;
        if (st) __syncthreads();
        #pragma unroll
        for (int c = t; c < 1024; c += 256) {
            int row = c >> 3, g = c & 7;
            uint4 hi, lo;
            split8(itemBase + (size_t)row * (SDIM * HDIM) + kbase + g * 8, &hi, &lo);
            *(uint4*)(&Ah[row * LDK + g * 8]) = hi;
            *(uint4*)(&Al[row * LDK + g * 8]) = lo;
            split8(wBase + (size_t)row * HDIM + kbase + g * 8, &hi, &lo);
            *(uint4*)(&Wh[row * LDK + g * 8]) = hi;
            *(uint4*)(&Wl[row * LDK + g * 8]) = lo;
        }
        __syncthreads();

        #pragma unroll
        for (int kk = 0; kk < 2; ++kk) {
            const int kof = kk * 32 + q * 8;
            short8 ah[4], al[4], bh[4], bl[4];
            #pragma unroll
            for (int tm = 0; tm < 4; ++tm) {
                int ro = (wm * 64 + tm * 16 + m0) * LDK + kof;
                ah[tm] = *(const short8*)(&Ah[ro]);
                al[tm] = *(const short8*)(&Al[ro]);
            }
            #pragma unroll
            for (int tn = 0; tn < 4; ++tn) {
                int ro = (wn * 64 + tn * 16 + m0) * LDK + kof;
                bh[tn] = *(const short8*)(&Wh[ro]);
                bl[tn] = *(const short8*)(&Wl[ro]);
            }
            #pragma unroll
            for (int tm = 0; tm < 4; ++tm)
                #pragma unroll
                for (int tn = 0; tn < 4; ++tn) {
                    acc[tm][tn] = __builtin_amdgcn_mfma_f32_16x16x32_bf16(
                        ah[tm], bl[tn], acc[tm][tn], 0, 0, 0);
                    acc[tm][tn] = __builtin_amdgcn_mfma_f32_16x16x32_bf16(
                        al[tm], bh[tn], acc[tm][tn], 0, 0, 0);
                    acc[tm][tn] = __builtin_amdgcn_mfma_f32_16x16x32_bf16(
                        ah[tm], bh[tn], acc[tm][tn], 0, 0, 0);
                }
        }
    }
    __syncthreads();

    #pragma unroll
    for (int tm = 0; tm < 4; ++tm) {
        #pragma unroll
        for (int tn = 0; tn < 4; ++tn) {
            int col = wn * 64 + tn * 16 + m0;
            #pragma unroll
            for (int rg = 0; rg < 4; ++rg) {
                int row = wm * 64 + tm * 16 + q * 4 + rg;
                ef[row * LDEF + col] = acc[tm][tn][rg];
            }
        }
    }
    __syncthreads();
    #pragma unroll
    for (int c = t; c < 4096; c += 256) {
        int row = c >> 5, cc = c & 31;
        int bl_ = bt * 128 + row;
        float4 v = *(const float4*)(&ef[row * LDEF + cc * 4]);
        *(float4*)(hat + (((size_t)bl_ * IDIM + ii) * SDIM + s) * HDIM + cc * 4) = v;
    }
}

// ---------------------------------------------------------------------------
// Kernel 2 (v3): online-softmax fused routing. One block per b; 4 i-tiles
// sequential with register prefetch. 1024 threads / 16 waves; wave wv owns
// s in {wv, wv+16, ...}. Per iteration ONE pass over hs computes delta-dot,
// cw update, online softmax (max/denom), and masked weighted-sum together.
// LDS ~116.5 KB -> 1 block/CU, but only ~10 barrier-phases per tile.
// ---------------------------------------------------------------------------
__global__ __launch_bounds__(1024) void routing3(const float* __restrict__ hat,
                                                 const int* __restrict__ mask,
                                                 float* __restrict__ out, int b0) {
    __shared__ float hs[SDIM * LDEF];       // 105,600 B
    __shared__ float cw[SDIM];
    __shared__ int   mk[SDIM];
    __shared__ float mergeU[16 * HDIM];     // 8,192 B
    __shared__ float mergeM[16];
    __shared__ float mergeD[16];
    __shared__ float ics[HDIM];             // pre-squash ic
    __shared__ float icf[HDIM];             // squashed ic

    const int bl = blockIdx.x, b = b0 + bl;
    const int t = threadIdx.x, lane = t & 63, wv = t >> 6;
    const float* base = hat + (size_t)bl * IDIM * SDIM * HDIM;

    if (t < SDIM) mk[t] = mask[(size_t)b * SDIM + t];
    for (int c = t; c < 6400; c += 1024) {
        int row = c >> 5, cc = c & 31;
        *(float4*)(&hs[row * LDEF + cc * 4]) = *(const float4*)(base + (size_t)row * HDIM + cc * 4);
    }

    for (int ii = 0; ii < IDIM; ++ii) {
        float4 pf[7];
        if (ii + 1 < IDIM) {
            const float* nb = base + (size_t)(ii + 1) * SDIM * HDIM;
            #pragma unroll
            for (int j = 0; j < 7; ++j) {
                int c = t + j * 1024;
                if (c < 6400) pf[j] = *(const float4*)(nb + (size_t)(c >> 5) * HDIM + (c & 31) * 4);
            }
        }
        if (t < SDIM) cw[t] = 0.0f;
        __syncthreads();   // hs, cw, mk ready

        // ---- pass 0: sw uniform = 1/200 (masked excluded from numerator)
        {
            float u0 = 0.f, u1 = 0.f;
            for (int s = wv; s < SDIM; s += 16) {
                if (mk[s]) {
                    float2 h2 = *(const float2*)(&hs[s * LDEF + 2 * lane]);
                    u0 += h2.x; u1 += h2.y;
                }
            }
            mergeU[wv * HDIM + 2 * lane]     = u0;
            mergeU[wv * HDIM + 2 * lane + 1] = u1;
        }
        __syncthreads();
        if (t < HDIM) {
            float u = 0.f;
            #pragma unroll
            for (int wg = 0; wg < 16; ++wg) u += mergeU[wg * HDIM + t];
            ics[t] = u * (1.0f / 200.0f);
        }
        __syncthreads();
        if (wv == 0) {
            float i0 = ics[lane], i1 = ics[lane + 64];
            float p = i0 * i0 + i1 * i1;
            #pragma unroll
            for (int off = 32; off > 0; off >>= 1) p += __shfl_xor(p, off);
            float fac = p / (1.0f + p) / sqrtf(p + 1e-9f);
            icf[lane] = i0 * fac;
            icf[lane + 64] = i1 * fac;
        }
        __syncthreads();

        // ---- iterations 1,2: fused delta + online softmax + accumulate
        for (int iter = 1; iter < 3; ++iter) {
            float c0 = icf[2 * lane], c1 = icf[2 * lane + 1];
            float m = -1e30f, D = 0.f, u0 = 0.f, u1 = 0.f;
            for (int s = wv; s < SDIM; s += 16) {
                float2 h2 = *(const float2*)(&hs[s * LDEF + 2 * lane]);
                float d = fmaf(h2.x, c0, h2.y * c1);
                #pragma unroll
                for (int off = 32; off > 0; off >>= 1) d += __shfl_xor(d, off);
                float l = cw[s] + d;           // cw read (broadcast) then owned write
                if (lane == 0) cw[s] = l;
                float mn = fmaxf(m, l);
                float r = __expf(m - mn);      // first s: exp(-huge) = 0, scales empty acc
                float e = __expf(l - mn);
                D = D * r + e;
                float g = mk[s] ? e : 0.f;
                u0 = fmaf(u0, r, g * h2.x);
                u1 = fmaf(u1, r, g * h2.y);
                m = mn;
            }
            if (lane == 0) { mergeM[wv] = m; mergeD[wv] = D; }
            mergeU[wv * HDIM + 2 * lane]     = u0;
            mergeU[wv * HDIM + 2 * lane + 1] = u1;
            __syncthreads();   // all hs reads of this pass complete

            if (t < HDIM) {
                float M = -1e30f;
                #pragma unroll
                for (int wg = 0; wg < 16; ++wg) M = fmaxf(M, mergeM[wg]);
                float Dg = 0.f, u = 0.f;
                #pragma unroll
                for (int wg = 0; wg < 16; ++wg) {
                    float rr = __expf(mergeM[wg] - M);
                    Dg = fmaf(mergeD[wg], rr, Dg);
                    u  = fmaf(mergeU[wg * HDIM + t], rr, u);
                }
                ics[t] = u / Dg;
            }
            // install prefetched next tile while t<128 merges (hs reads are done)
            if (iter == 2 && ii + 1 < IDIM) {
                #pragma unroll
                for (int j = 0; j < 7; ++j) {
                    int c = t + j * 1024;
                    if (c < 6400) *(float4*)(&hs[(c >> 5) * LDEF + (c & 31) * 4]) = pf[j];
                }
            }
            __syncthreads();
            if (wv == 0) {
                float i0 = ics[lane], i1 = ics[lane + 64];
                float p = i0 * i0 + i1 * i1;
                #pragma unroll
                for (int off = 32; off > 0; off >>= 1) p += __shfl_xor(p, off);
                float fac = p / (1.0f + p) / sqrtf(p + 1e-9f);
                if (iter < 2) {
                    icf[lane] = i0 * fac;
                    icf[lane + 64] = i1 * fac;
                } else {
                    out[((size_t)b * IDIM + ii) * HDIM + lane]      = i0 * fac;
                    out[((size_t)b * IDIM + ii) * HDIM + lane + 64] = i1 * fac;
                }
            }
            __syncthreads();
        }
    }
}

extern "C" void kernel_launch(void* const* d_in, const int* in_sizes, int n_in,
                              void* d_out, int out_size, void* d_ws, size_t ws_size,
                              hipStream_t stream) {
    const float* item = nullptr;
    const int*   msk  = nullptr;
    const float* w    = nullptr;
    for (int i = 0; i < n_in; ++i) {
        if (in_sizes[i] == BDIM * SDIM * HDIM)             item = (const float*)d_in[i];
        else if (in_sizes[i] == BDIM * SDIM)               msk  = (const int*)d_in[i];
        else if (in_sizes[i] == SDIM * IDIM * HDIM * HDIM) w    = (const float*)d_in[i];
    }
    if (!item) item = (const float*)d_in[0];
    if (!msk)  msk  = (const int*)d_in[1];
    if (!w)    w    = (const float*)d_in[2];

    float* hat = (float*)d_ws;                 // (B,I,S,H) fp32, 419.4 MB (fits: R4)
    float* out = (float*)d_out;

    const size_t perB = (size_t)IDIM * SDIM * HDIM * sizeof(float);
    size_t hatCap = ws_size / perB;
    int chunk = (hatCap >= BDIM) ? BDIM : (int)((hatCap / 128) * 128);
    if (chunk < 128) chunk = 128;
    for (int bb = 0; bb < BDIM; bb += chunk) {
        int cb = (BDIM - bb < chunk) ? (BDIM - bb) : chunk;
        int nbt = cb / 128;
        hat_gemm<<<SDIM * IDIM * nbt, 256, 0, stream>>>(item, w, hat, bb, nbt);
        routing3<<<cb, 1024, 0, stream>>>(hat, msk, out, bb);
    }
}

// Round 7
// 456.145 us; speedup vs baseline: 1.6364x; 1.4629x over previous
//
#include <hip/hip_runtime.h>
#include <hip/hip_bf16.h>
#include <cstdint>

#define SDIM 200
#define HDIM 128
#define IDIM 4
#define BDIM 1024
#define LDK 72      // bf16 staging leading dim per 64-wide K-half (144 B rows)
#define LDEF 132    // fp32 epilogue leading dim (528 B rows)

typedef __attribute__((ext_vector_type(8))) short short8;
typedef __attribute__((ext_vector_type(4))) float f32x4;

__device__ __forceinline__ ushort f32_to_bf16u(float f) {
    uint32_t u = __builtin_bit_cast(uint32_t, f);
    u += 0x7FFFu + ((u >> 16) & 1u);   // RNE
    return (ushort)(u >> 16);
}
__device__ __forceinline__ float bf16u_to_f32(ushort h) {
    uint32_t u = ((uint32_t)h) << 16;
    return __builtin_bit_cast(float, u);
}
__device__ __forceinline__ void split8(const float* p, uint4* hi, uint4* lo) {
    union { ushort u[8]; uint4 v; } xh, xl;
    #pragma unroll
    for (int j = 0; j < 8; ++j) {
        float f = p[j];
        ushort h = f32_to_bf16u(f);
        float r = f - bf16u_to_f32(h);
        xh.u[j] = h;
        xl.u[j] = f32_to_bf16u(r);
    }
    *hi = xh.v; *lo = xl.v;
}

// ---------------------------------------------------------------------------
// Kernel 1 (R4-proven): hat[bl,i,s,h'] = sum_h item*w, split-bf16 3-stream MFMA.
// ---------------------------------------------------------------------------
__global__ __launch_bounds__(256) void hat_gemm(const float* __restrict__ item,
                                                const float* __restrict__ w,
                                                float* __restrict__ hat,
                                                int b0, int nbt) {
    __shared__ ushort lds[4 * 128 * LDK];
    ushort* Ah = lds;
    ushort* Al = lds + 128 * LDK;
    ushort* Wh = lds + 2 * 128 * LDK;
    ushort* Wl = lds + 3 * 128 * LDK;
    float*  ef = (float*)lds;

    const int blk = blockIdx.x;
    const int s  = blk / (IDIM * nbt);
    const int r  = blk % (IDIM * nbt);
    const int ii = r / nbt;
    const int bt = r % nbt;
    const int t  = threadIdx.x;

    const float* itemBase = item + ((size_t)(b0 + bt * 128) * SDIM + s) * HDIM;
    const float* wBase    = w + ((size_t)s * (IDIM * HDIM) + (size_t)ii * HDIM) * HDIM;

    const int wave = t >> 6, lane = t & 63;
    const int wm = wave >> 1, wn = wave & 1;
    const int m0 = lane & 15, q = lane >> 4;

    f32x4 acc[4][4];
    #pragma unroll
    for (int tm = 0; tm < 4; ++tm)
        #pragma unroll
        for (int tn = 0; tn < 4; ++tn)
            acc[tm][tn] = (f32x4){0.f, 0.f, 0.f, 0.f};

    #pragma unroll
    for (int st = 0; st < 2; ++st) {
        const int kbase = st * 64;
        if (st) __syncthreads();
        #pragma unroll
        for (int c = t; c < 1024; c += 256) {
            int row = c >> 3, g = c & 7;
            uint4 hi, lo;
            split8(itemBase + (size_t)row * (SDIM * HDIM) + kbase + g * 8, &hi, &lo);
            *(uint4*)(&Ah[row * LDK + g * 8]) = hi;
            *(uint4*)(&Al[row * LDK + g * 8]) = lo;
            split8(wBase + (size_t)row * HDIM + kbase + g * 8, &hi, &lo);
            *(uint4*)(&Wh[row * LDK + g * 8]) = hi;
            *(uint4*)(&Wl[row * LDK + g * 8]) = lo;
        }
        __syncthreads();

        #pragma unroll
        for (int kk = 0; kk < 2; ++kk) {
            const int kof = kk * 32 + q * 8;
            short8 ah[4], al[4], bh[4], bl[4];
            #pragma unroll
            for (int tm = 0; tm < 4; ++tm) {
                int ro = (wm * 64 + tm * 16 + m0) * LDK + kof;
                ah[tm] = *(const short8*)(&Ah[ro]);
                al[tm] = *(const short8*)(&Al[ro]);
            }
            #pragma unroll
            for (int tn = 0; tn < 4; ++tn) {
                int ro = (wn * 64 + tn * 16 + m0) * LDK + kof;
                bh[tn] = *(const short8*)(&Wh[ro]);
                bl[tn] = *(const short8*)(&Wl[ro]);
            }
            #pragma unroll
            for (int tm = 0; tm < 4; ++tm)
                #pragma unroll
                for (int tn = 0; tn < 4; ++tn) {
                    acc[tm][tn] = __builtin_amdgcn_mfma_f32_16x16x32_bf16(
                        ah[tm], bl[tn], acc[tm][tn], 0, 0, 0);
                    acc[tm][tn] = __builtin_amdgcn_mfma_f32_16x16x32_bf16(
                        al[tm], bh[tn], acc[tm][tn], 0, 0, 0);
                    acc[tm][tn] = __builtin_amdgcn_mfma_f32_16x16x32_bf16(
                        ah[tm], bh[tn], acc[tm][tn], 0, 0, 0);
                }
        }
    }
    __syncthreads();

    #pragma unroll
    for (int tm = 0; tm < 4; ++tm) {
        #pragma unroll
        for (int tn = 0; tn < 4; ++tn) {
            int col = wn * 64 + tn * 16 + m0;
            #pragma unroll
            for (int rg = 0; rg < 4; ++rg) {
                int row = wm * 64 + tm * 16 + q * 4 + rg;
                ef[row * LDEF + col] = acc[tm][tn][rg];
            }
        }
    }
    __syncthreads();
    #pragma unroll
    for (int c = t; c < 4096; c += 256) {
        int row = c >> 5, cc = c & 31;
        int bl_ = bt * 128 + row;
        float4 v = *(const float4*)(&ef[row * LDEF + cc * 4]);
        *(float4*)(hat + (((size_t)bl_ * IDIM + ii) * SDIM + s) * HDIM + cc * 4) = v;
    }
}

// ---------------------------------------------------------------------------
// Kernel 2 (v4): register-resident tile routing. One block per (b,i), 256 thr.
// Thread t owns s-group sg=t>>5 (s = sg+8j, j<25) x h-quad hq=(t&31)*4:
// float4 pf[25] = 100 VGPRs. LDS ~6 KB -> 3 blocks/CU overlap phases.
// ---------------------------------------------------------------------------
__global__ __launch_bounds__(256, 3) void routing4(const float* __restrict__ hat,
                                                   const int* __restrict__ mask,
                                                   float* __restrict__ out, int b0) {
    __shared__ float cw[SDIM];
    __shared__ float eall[SDIM];
    __shared__ float ew[SDIM];
    __shared__ float icp[8 * HDIM];
    __shared__ float ic[HDIM];
    __shared__ float icf[HDIM];
    __shared__ int   mk[SDIM];

    const int blk = blockIdx.x;
    const int bl = blk >> 2, ii = blk & 3;
    const int b = b0 + bl;
    const int t = threadIdx.x, lane = t & 63, wv = t >> 6;
    const int hq = (t & 31) * 4;
    const int sg = t >> 5;
    const float* base = hat + ((size_t)bl * IDIM + ii) * (SDIM * HDIM);

    if (t < SDIM) mk[t] = mask[(size_t)b * SDIM + t];

    // load tile into registers (25 independent dwordx4 loads, coalesced)
    float4 pf[25];
    #pragma unroll
    for (int j = 0; j < 25; ++j)
        pf[j] = *(const float4*)(base + (size_t)(sg + 8 * j) * HDIM + hq);
    __syncthreads();   // mk ready

    // ---- pass 0: uniform sw = 1/200, masked numerator
    {
        float4 u = {0.f, 0.f, 0.f, 0.f};
        #pragma unroll
        for (int j = 0; j < 25; ++j) {
            if (mk[sg + 8 * j]) {
                u.x += pf[j].x; u.y += pf[j].y; u.z += pf[j].z; u.w += pf[j].w;
            }
        }
        *(float4*)(&icp[sg * HDIM + hq]) = u;
    }
    __syncthreads();
    if (t < HDIM) {
        float v = 0.f;
        #pragma unroll
        for (int g = 0; g < 8; ++g) v += icp[g * HDIM + t];
        ic[t] = v * (1.0f / 200.0f);
    }
    __syncthreads();
    if (wv == 0) {
        float i0 = ic[lane], i1 = ic[lane + 64];
        float p = i0 * i0 + i1 * i1;
        #pragma unroll
        for (int off = 32; off > 0; off >>= 1) p += __shfl_xor(p, off);
        float fac = p / (1.0f + p) / sqrtf(p + 1e-9f);
        icf[lane] = i0 * fac;
        icf[lane + 64] = i1 * fac;
    }
    __syncthreads();

    for (int iter = 1; iter <= 2; ++iter) {
        // A: delta[s] = <hat_s, icf>; 25 independent 5-shuffle reductions
        float4 c4 = *(const float4*)(&icf[hq]);
        #pragma unroll
        for (int j = 0; j < 25; ++j) {
            float d = fmaf(pf[j].x, c4.x, fmaf(pf[j].y, c4.y,
                      fmaf(pf[j].z, c4.z, pf[j].w * c4.w)));
            d += __shfl_xor(d, 16);
            d += __shfl_xor(d, 8);
            d += __shfl_xor(d, 4);
            d += __shfl_xor(d, 2);
            d += __shfl_xor(d, 1);
            if ((t & 31) == 0) {
                int s = sg + 8 * j;
                cw[s] = (iter == 1) ? d : cw[s] + d;
            }
        }
        __syncthreads();

        // B1: block max (redundant per wave), exp
        float m = fmaxf(cw[lane], fmaxf(cw[lane + 64], cw[lane + 128]));
        if (lane < SDIM - 192) m = fmaxf(m, cw[lane + 192]);
        #pragma unroll
        for (int off = 32; off > 0; off >>= 1) m = fmaxf(m, __shfl_xor(m, off));
        if (t < SDIM) {
            float e = __expf(cw[t] - m);
            eall[t] = e;
            ew[t] = mk[t] ? e : 0.0f;
        }
        __syncthreads();

        // B2: denominator (redundant per wave; includes masked entries)
        float D = eall[lane] + eall[lane + 64] + eall[lane + 128]
                + ((lane < SDIM - 192) ? eall[lane + 192] : 0.0f);
        #pragma unroll
        for (int off = 32; off > 0; off >>= 1) D += __shfl_xor(D, off);

        // C: numerator u[h] = sum_s ew[s]*hat[s,h] from registers
        {
            float4 u = {0.f, 0.f, 0.f, 0.f};
            #pragma unroll
            for (int j = 0; j < 25; ++j) {
                float wgt = ew[sg + 8 * j];
                u.x = fmaf(wgt, pf[j].x, u.x);
                u.y = fmaf(wgt, pf[j].y, u.y);
                u.z = fmaf(wgt, pf[j].z, u.z);
                u.w = fmaf(wgt, pf[j].w, u.w);
            }
            *(float4*)(&icp[sg * HDIM + hq]) = u;
        }
        __syncthreads();

        // D: merge 8 s-group partials, divide by denominator
        if (t < HDIM) {
            float v = 0.f;
            #pragma unroll
            for (int g = 0; g < 8; ++g) v += icp[g * HDIM + t];
            ic[t] = v / D;
        }
        __syncthreads();

        // E: squash; iter1 -> icf, iter2 -> output
        if (wv == 0) {
            float i0 = ic[lane], i1 = ic[lane + 64];
            float p = i0 * i0 + i1 * i1;
            #pragma unroll
            for (int off = 32; off > 0; off >>= 1) p += __shfl_xor(p, off);
            float fac = p / (1.0f + p) / sqrtf(p + 1e-9f);
            if (iter == 1) {
                icf[lane] = i0 * fac;
                icf[lane + 64] = i1 * fac;
            } else {
                out[((size_t)b * IDIM + ii) * HDIM + lane]      = i0 * fac;
                out[((size_t)b * IDIM + ii) * HDIM + lane + 64] = i1 * fac;
            }
        }
        if (iter == 1) __syncthreads();
    }
}

extern "C" void kernel_launch(void* const* d_in, const int* in_sizes, int n_in,
                              void* d_out, int out_size, void* d_ws, size_t ws_size,
                              hipStream_t stream) {
    const float* item = nullptr;
    const int*   msk  = nullptr;
    const float* w    = nullptr;
    for (int i = 0; i < n_in; ++i) {
        if (in_sizes[i] == BDIM * SDIM * HDIM)             item = (const float*)d_in[i];
        else if (in_sizes[i] == BDIM * SDIM)               msk  = (const int*)d_in[i];
        else if (in_sizes[i] == SDIM * IDIM * HDIM * HDIM) w    = (const float*)d_in[i];
    }
    if (!item) item = (const float*)d_in[0];
    if (!msk)  msk  = (const int*)d_in[1];
    if (!w)    w    = (const float*)d_in[2];

    float* hat = (float*)d_ws;                 // (B,I,S,H) fp32, 419.4 MB (fits: R4)
    float* out = (float*)d_out;

    const size_t perB = (size_t)IDIM * SDIM * HDIM * sizeof(float);
    size_t hatCap = ws_size / perB;
    int chunk = (hatCap >= BDIM) ? BDIM : (int)((hatCap / 128) * 128);
    if (chunk < 128) chunk = 128;
    for (int bb = 0; bb < BDIM; bb += chunk) {
        int cb = (BDIM - bb < chunk) ? (BDIM - bb) : chunk;
        int nbt = cb / 128;
        hat_gemm<<<SDIM * IDIM * nbt, 256, 0, stream>>>(item, w, hat, bb, nbt);
        routing4<<<cb * IDIM, 256, 0, stream>>>(hat, msk, out, bb);
    }
}